// Round 4
// baseline (442.367 us; speedup 1.0000x reference)
//
#include <hip/hip_runtime.h>
#include <math.h>

#define BATCH 8
#define N 2048
#define D 128
#define ST 4000

#define BI 32
#define TJ 64
#define NT 256
#define NITER (N / TJ)   // 32

// ---------------------------------------------------------------------------
// Kernel 0: per-batch bitonic sort of (val,pos). key = (val<<11)|pos.
// Sorted-j gathers span ~9 cache lines per 64 columns instead of ~56.
// Matmul is j-permutation invariant since x rows are permuted identically.
// ---------------------------------------------------------------------------
__global__ __launch_bounds__(1024) void sort_kernel(
    const int* __restrict__ stk_ten,
    int* __restrict__ sval,
    int* __restrict__ spos)
{
    __shared__ unsigned keys[N];
    const int b = blockIdx.x;
    const int t = threadIdx.x;
    const int* idxb = stk_ten + b * N;
    for (int j = t; j < N; j += 1024)
        keys[j] = ((unsigned)idxb[j] << 11) | (unsigned)j;
    __syncthreads();
    for (int k = 2; k <= N; k <<= 1) {
        for (int jj = k >> 1; jj > 0; jj >>= 1) {
            for (int ix = t; ix < N; ix += 1024) {
                const int ixj = ix ^ jj;
                if (ixj > ix) {
                    const unsigned a = keys[ix], c = keys[ixj];
                    const bool up = ((ix & k) == 0);
                    if ((a > c) == up) { keys[ix] = c; keys[ixj] = a; }
                }
            }
            __syncthreads();
        }
    }
    for (int j = t; j < N; j += 1024) {
        const unsigned kk = keys[j];
        sval[b * N + j] = (int)(kk >> 11);
        spos[b * N + j] = (int)(kk & 2047u);
    }
}

// ---------------------------------------------------------------------------
// Fused kernel: gather + online (unnormalized) softmax + GEMM, software-
// pipelined. exp(w) needs no max subtraction: w = |N(0,1)| <= ~6 -> e^w <=
// ~403, safe in fp32. Denominator l accumulated per row via wave shuffles.
// Per iteration: tile t's x rows + M/W values already sit in VGPRs
// (prefetched before tile t-1's FMA phase, which hides the ~600-900 cyc
// scattered-gather latency). LDS tiles single-buffered (two barriers order
// write->read and read->overwrite); index arrays double-buffered.
// ---------------------------------------------------------------------------
__global__ __launch_bounds__(NT, 3) void fused_gemm_kernel(
    const float* __restrict__ x,
    const int* __restrict__ stk_ten,
    const float* __restrict__ stk_matrix,
    const float* __restrict__ stk_weight,
    const int* __restrict__ sval,
    const int* __restrict__ spos,
    float* __restrict__ out)
{
    __shared__ float xs[TJ * D];       // 32 KB [jl][d]
    __shared__ float cs[BI * TJ];      // 8 KB  [il][jl]
    __shared__ int   sv_s[2][TJ];
    __shared__ int   sp_s[2][TJ];
    __shared__ int   ri_s[BI];
    __shared__ float l_s[BI];

    const int t  = threadIdx.x;
    const int b  = blockIdx.x >> 6;        // / (N/BI = 64)
    const int it = blockIdx.x & 63;
    const int i0 = it * BI;

    if (t < BI) ri_s[t] = stk_ten[b * N + i0 + t];

    const int tx  = t & 31;
    const int ty  = t >> 5;                // 0..7
    const int d0  = tx * 4;
    const int il0 = ty * 4;
    const int jlg = t & 63;                // coef column slot (lane-consecutive)
    const int wg  = t >> 6;                // 0..3 (wave id; owns rows wg+4k)
    const int r0  = ty;                    // staging row group
    const int c4  = tx;                    // staging col (float4)

    const float4* xg4 = (const float4*)(x + ((size_t)(b * N) << 7));
    const int* svb = sval + b * N;
    const int* spb = spos + b * N;

    float acc[4][4];
    #pragma unroll
    for (int r = 0; r < 4; ++r)
        #pragma unroll
        for (int k = 0; k < 4; ++k) acc[r][k] = 0.0f;
    float l_run[8];
    #pragma unroll
    for (int k = 0; k < 8; ++k) l_run[k] = 0.0f;

    // tile-0 indices
    if (t < TJ) { sv_s[0][t] = svb[t]; sp_s[0][t] = spb[t]; }
    __syncthreads();

    // prefetch registers (tile 0)
    float4 xr[8];
    float  mr[8], wr[8];
    int    pjr, cjr;
    {
        cjr = sv_s[0][jlg]; pjr = sp_s[0][jlg];
        #pragma unroll
        for (int p = 0; p < 8; ++p) {
            const int sp = sp_s[0][r0 + 8 * p];
            xr[p] = xg4[(size_t)sp * 32 + c4];
        }
        #pragma unroll
        for (int k = 0; k < 8; ++k) {
            const size_t off = (size_t)ri_s[wg + 4 * k] * ST + cjr;
            mr[k] = stk_matrix[off];
            wr[k] = stk_weight[off];
        }
    }

    for (int jt = 0; jt < NITER; ++jt) {
        const int buf = jt & 1, nb = buf ^ 1;

        // next tile's indices -> other buffer (read only after sync2)
        if (jt + 1 < NITER && t < TJ) {
            sv_s[nb][t] = svb[(jt + 1) * TJ + t];
            sp_s[nb][t] = spb[(jt + 1) * TJ + t];
        }

        // phase A: coefficients + online denominator (tile jt, data in regs)
        float creg[8];
        #pragma unroll
        for (int k = 0; k < 8; ++k) {
            const bool diag = (pjr == i0 + wg + 4 * k);
            const float w = diag ? 0.0f : fabsf(wr[k]);
            const float e = __expf(w);       // diag contributes exp(0)=1 to l
            creg[k] = diag ? 0.0f : mr[k] * e;
            float s = e;
            #pragma unroll
            for (int dd = 1; dd < 64; dd <<= 1) s += __shfl_xor(s, dd, 64);
            l_run[k] += s;
        }

        __syncthreads();                     // prior FMA done reading xs/cs

        // phase B: write LDS tiles from registers
        #pragma unroll
        for (int p = 0; p < 8; ++p)
            ((float4*)xs)[(r0 + 8 * p) * 32 + c4] = xr[p];
        #pragma unroll
        for (int k = 0; k < 8; ++k)
            cs[(wg + 4 * k) * TJ + jlg] = creg[k];

        __syncthreads();                     // tiles visible; idx[nb] visible

        // phase C: issue prefetch for tile jt+1 (lands during FMA below)
        if (jt + 1 < NITER) {
            cjr = sv_s[nb][jlg]; pjr = sp_s[nb][jlg];
            #pragma unroll
            for (int p = 0; p < 8; ++p) {
                const int sp = sp_s[nb][r0 + 8 * p];
                xr[p] = xg4[(size_t)sp * 32 + c4];
            }
            #pragma unroll
            for (int k = 0; k < 8; ++k) {
                const size_t off = (size_t)ri_s[wg + 4 * k] * ST + cjr;
                mr[k] = stk_matrix[off];
                wr[k] = stk_weight[off];
            }
        }

        // phase D: register-blocked matmul on tile jt
        #pragma unroll 2
        for (int jc = 0; jc < TJ; jc += 4) {
            float4 xv[4], cv[4];
            #pragma unroll
            for (int q = 0; q < 4; ++q)
                xv[q] = *(const float4*)(xs + (jc + q) * D + d0);
            #pragma unroll
            for (int r = 0; r < 4; ++r)
                cv[r] = *(const float4*)(cs + (il0 + r) * TJ + jc);
            #pragma unroll
            for (int q = 0; q < 4; ++q) {
                const float xq[4] = {xv[q].x, xv[q].y, xv[q].z, xv[q].w};
                const float cq[4] = {((const float*)&cv[0])[q],
                                     ((const float*)&cv[1])[q],
                                     ((const float*)&cv[2])[q],
                                     ((const float*)&cv[3])[q]};
                #pragma unroll
                for (int r = 0; r < 4; ++r)
                    #pragma unroll
                    for (int k = 0; k < 4; ++k)
                        acc[r][k] = fmaf(cq[r], xq[k], acc[r][k]);
            }
        }
    }

    // epilogue: publish denominators (replicated across lanes), normalize
    #pragma unroll
    for (int k = 0; k < 8; ++k)
        if (jlg == k) l_s[wg + 4 * k] = l_run[k];
    __syncthreads();
    #pragma unroll
    for (int r = 0; r < 4; ++r) {
        const float linv = 1.0f / l_s[il0 + r];
        float4 v;
        v.x = acc[r][0] * linv; v.y = acc[r][1] * linv;
        v.z = acc[r][2] * linv; v.w = acc[r][3] * linv;
        *(float4*)(out + ((size_t)(b * N + i0 + il0 + r) << 7) + d0) = v;
    }
}

extern "C" void kernel_launch(void* const* d_in, const int* in_sizes, int n_in,
                              void* d_out, int out_size, void* d_ws, size_t ws_size,
                              hipStream_t stream) {
    const float* x          = (const float*)d_in[0];
    const int*   stk_ten    = (const int*)d_in[1];
    const float* stk_matrix = (const float*)d_in[2];
    const float* stk_weight = (const float*)d_in[3];
    float* out = (float*)d_out;

    int* sval = (int*)d_ws;                 // 64 KB
    int* spos = sval + BATCH * N;           // 64 KB

    sort_kernel<<<BATCH, 1024, 0, stream>>>(stk_ten, sval, spos);
    fused_gemm_kernel<<<BATCH * (N / BI), NT, 0, stream>>>(
        x, stk_ten, stk_matrix, stk_weight, sval, spos, out);
}

// Round 5
// 259.180 us; speedup vs baseline: 1.7068x; 1.7068x over previous
//
#include <hip/hip_runtime.h>
#include <math.h>

#define BATCH 8
#define N 2048
#define D 128
#define ST 4000

#define BI 32
#define TJ 64
#define NT 256
#define NITER (N / TJ)   // 32
#define TJP 72           // LDS row stride in halves: 144 B = 16B-aligned, uniform banks

typedef short bf16x8 __attribute__((ext_vector_type(8)));
typedef float f32x16 __attribute__((ext_vector_type(16)));

__device__ __forceinline__ unsigned short f2bf(float f) {
    union { float f; unsigned u; } v; v.f = f;
    const unsigned r = v.u + 0x7FFFu + ((v.u >> 16) & 1u);   // RNE
    return (unsigned short)(r >> 16);
}

// ---------------------------------------------------------------------------
// Kernel 0: per-batch bitonic sort of (val,pos). key = (val<<11)|pos.
// Sorted-j gathers span ~9 cache lines per 64 columns instead of ~56.
// ---------------------------------------------------------------------------
__global__ __launch_bounds__(1024) void sort_kernel(
    const int* __restrict__ stk_ten,
    int* __restrict__ sval,
    int* __restrict__ spos)
{
    __shared__ unsigned keys[N];
    const int b = blockIdx.x;
    const int t = threadIdx.x;
    const int* idxb = stk_ten + b * N;
    for (int j = t; j < N; j += 1024)
        keys[j] = ((unsigned)idxb[j] << 11) | (unsigned)j;
    __syncthreads();
    for (int k = 2; k <= N; k <<= 1) {
        for (int jj = k >> 1; jj > 0; jj >>= 1) {
            for (int ix = t; ix < N; ix += 1024) {
                const int ixj = ix ^ jj;
                if (ixj > ix) {
                    const unsigned a = keys[ix], c = keys[ixj];
                    const bool up = ((ix & k) == 0);
                    if ((a > c) == up) { keys[ix] = c; keys[ixj] = a; }
                }
            }
            __syncthreads();
        }
    }
    for (int j = t; j < N; j += 1024) {
        const unsigned kk = keys[j];
        sval[b * N + j] = (int)(kk >> 11);
        spos[b * N + j] = (int)(kk & 2047u);
    }
}

// ---------------------------------------------------------------------------
// Kernel 1: build xT[b][d][j_sorted] = bf16(x[b][spos[j]][d]).  4 MB.
// Makes the fused kernel's B-tile staging a plain coalesced 16B copy.
// ---------------------------------------------------------------------------
__global__ __launch_bounds__(256) void xt_kernel(
    const float* __restrict__ x,
    const int* __restrict__ spos,
    unsigned short* __restrict__ xT)
{
    __shared__ float xs[TJ][129];     // pad: transpose reads 2-way max
    __shared__ int sp_s[TJ];
    const int t  = threadIdx.x;
    const int b  = blockIdx.x >> 5;   // / 32
    const int jt = blockIdx.x & 31;
    const int j0 = jt * TJ;
    if (t < TJ) sp_s[t] = spos[b * N + j0 + t];
    __syncthreads();
    const int tx = t & 31, ty = t >> 5;
    const float* xb = x + (size_t)b * N * D;
    #pragma unroll
    for (int p = 0; p < 8; ++p) {
        const int r = ty + 8 * p;
        const float* src = xb + (size_t)sp_s[r] * D;
        #pragma unroll
        for (int i = 0; i < 4; ++i)
            xs[r][tx + 32 * i] = src[tx + 32 * i];
    }
    __syncthreads();
    const int jp = t & 31, dd0 = t >> 5;
    unsigned short* xTb = xT + (size_t)b * D * N;
    #pragma unroll
    for (int q = 0; q < 16; ++q) {
        const int dd = dd0 + 8 * q;
        const unsigned lo = f2bf(xs[2 * jp][dd]);
        const unsigned hi = f2bf(xs[2 * jp + 1][dd]);
        *(unsigned*)(xTb + (size_t)dd * N + j0 + 2 * jp) = (hi << 16) | lo;
    }
}

// ---------------------------------------------------------------------------
// Kernel 2: fused gather + online softmax + bf16-MFMA GEMM.
// 256 thr, BI=32 rows x D=128 cols per block; wave w owns O[i0:+32][32w:+32].
// Per tile: stage xT slab (coalesced b128), compute coef tile from PREFETCHED
// M/W regs (16 floats only -> no spill), l via wave butterflies; then issue
// tile t+1's scattered gathers and run 4 chained 32x32x16 MFMAs (K=64).
// Fragments: A = cs[m=lane&31][k], B = xT[n=lane&31][k] -- both contiguous
// b128 at stride 144 B (uniform bank phases).
// ---------------------------------------------------------------------------
__global__ __launch_bounds__(NT, 2) void fused_kernel(
    const unsigned short* __restrict__ xT,
    const int* __restrict__ stk_ten,
    const float* __restrict__ stk_matrix,
    const float* __restrict__ stk_weight,
    const int* __restrict__ sval,
    const int* __restrict__ spos,
    float* __restrict__ out)
{
    __shared__ __align__(16) unsigned short xs[D * TJP];   // 18.0 KB
    __shared__ __align__(16) unsigned short cs[BI * TJP];  //  4.5 KB
    __shared__ int   sv_s[2][TJ], sp_s[2][TJ], ri_s[BI];
    __shared__ float l_s[BI];

    const int t    = threadIdx.x;
    const int b    = blockIdx.x >> 6;
    const int i0   = (blockIdx.x & 63) * BI;
    const int lane = t & 63;
    const int w    = t >> 6;          // wave id 0..3

    if (t < BI) ri_s[t] = stk_ten[b * N + i0 + t];
    const int* svb = sval + b * N;
    const int* spb = spos + b * N;
    if (t < TJ) { sv_s[0][t] = svb[t]; sp_s[0][t] = spb[t]; }
    __syncthreads();

    // prefetch scattered M/W for tile 0 (wave-uniform row, sorted columns)
    int cj = sv_s[0][lane], pj = sp_s[0][lane];
    float mg[8], wv[8];
    #pragma unroll
    for (int k = 0; k < 8; ++k) {
        const size_t off = (size_t)ri_s[w + 4 * k] * ST + cj;
        mg[k] = stk_matrix[off];
        wv[k] = stk_weight[off];
    }

    f32x16 acc;
    #pragma unroll
    for (int r = 0; r < 16; ++r) acc[r] = 0.0f;
    float l_run[8] = {0, 0, 0, 0, 0, 0, 0, 0};

    const unsigned short* xTb = xT + (size_t)b * D * N;

    for (int jt = 0; jt < NITER; ++jt) {
        const int nb = (jt & 1) ^ 1;
        const int j0 = jt * TJ;

        // stage x slab: 1024 16B chunks, coalesced
        #pragma unroll
        for (int p = 0; p < 4; ++p) {
            const int c = t + p * 256;
            const int row = c >> 3, cno = c & 7;
            *(uint4*)(xs + row * TJP + cno * 8) =
                *(const uint4*)(xTb + (size_t)row * N + j0 + cno * 8);
        }
        // next tile's indices into the other buffer
        if (jt + 1 < NITER && t < TJ) {
            sv_s[nb][t] = svb[j0 + TJ + t];
            sp_s[nb][t] = spb[j0 + TJ + t];
        }
        // coefficients for tile jt from prefetched regs + online denominator
        #pragma unroll
        for (int k = 0; k < 8; ++k) {
            const int row = w + 4 * k;
            const bool diag = (pj == i0 + row);
            const float ww = diag ? 0.0f : fabsf(wv[k]);
            const float e = __expf(ww);          // diag contributes exp(0)=1
            const float c = diag ? 0.0f : mg[k] * e;
            cs[row * TJP + lane] = f2bf(c);
            float s = e;
            #pragma unroll
            for (int dd = 1; dd < 64; dd <<= 1) s += __shfl_xor(s, dd, 64);
            l_run[k] += s;
        }
        __syncthreads();                         // xs/cs/idx[nb] visible

        // issue tile jt+1's scattered gathers; land during MFMA below
        if (jt + 1 < NITER) {
            cj = sv_s[nb][lane]; pj = sp_s[nb][lane];
            #pragma unroll
            for (int k = 0; k < 8; ++k) {
                const size_t off = (size_t)ri_s[w + 4 * k] * ST + cj;
                mg[k] = stk_matrix[off];
                wv[k] = stk_weight[off];
            }
        }

        // 4 chained MFMAs: K = 64
        #pragma unroll
        for (int ks = 0; ks < 4; ++ks) {
            const bf16x8 av = *(const bf16x8*)(cs + (lane & 31) * TJP + ks * 16 + (lane >> 5) * 8);
            const bf16x8 bv = *(const bf16x8*)(xs + (32 * w + (lane & 31)) * TJP + ks * 16 + (lane >> 5) * 8);
            acc = __builtin_amdgcn_mfma_f32_32x32x16_bf16(av, bv, acc, 0, 0, 0);
        }
        __syncthreads();                         // MFMA done before overwrite
    }

    // publish denominators (one lane per owned row), then normalize + store
    #pragma unroll
    for (int k = 0; k < 8; ++k)
        if (lane == k) l_s[w + 4 * k] = l_run[k];
    __syncthreads();

    const int col = lane & 31, q2 = lane >> 5;
    #pragma unroll
    for (int r = 0; r < 16; ++r) {
        const int row = (r & 3) + 8 * (r >> 2) + 4 * q2;
        const float linv = 1.0f / l_s[row];
        out[((size_t)(b * N + i0 + row) << 7) + 32 * w + col] = acc[r] * linv;
    }
}

extern "C" void kernel_launch(void* const* d_in, const int* in_sizes, int n_in,
                              void* d_out, int out_size, void* d_ws, size_t ws_size,
                              hipStream_t stream) {
    const float* x          = (const float*)d_in[0];
    const int*   stk_ten    = (const int*)d_in[1];
    const float* stk_matrix = (const float*)d_in[2];
    const float* stk_weight = (const float*)d_in[3];
    float* out = (float*)d_out;

    int* sval = (int*)d_ws;                              // 64 KB
    int* spos = sval + BATCH * N;                        // 64 KB
    unsigned short* xT = (unsigned short*)(spos + BATCH * N);  // 4 MB

    sort_kernel<<<BATCH, 1024, 0, stream>>>(stk_ten, sval, spos);
    xt_kernel<<<BATCH * (N / TJ), 256, 0, stream>>>(x, spos, xT);
    fused_kernel<<<BATCH * (N / BI), NT, 0, stream>>>(
        xT, stk_ten, stk_matrix, stk_weight, sval, spos, out);
}

// Round 6
// 243.461 us; speedup vs baseline: 1.8170x; 1.0646x over previous
//
#include <hip/hip_runtime.h>
#include <hip/hip_fp16.h>
#include <math.h>

#define BATCH 8
#define N 2048
#define D 128
#define ST 4000

#define TJ 64        // j-tile per K-step
#define IT 16        // i-rows per block (one i-tile, shared by 4 k-quarter waves)
#define KQ 4         // K-quarters = waves per block
#define TPW 8        // tiles per wave = N/TJ/KQ

typedef short bf16x8 __attribute__((ext_vector_type(8)));
typedef float f32x4  __attribute__((ext_vector_type(4)));

__device__ __forceinline__ unsigned short f2bf(float f) {
    union { float f; unsigned u; } v; v.f = f;
    const unsigned r = v.u + 0x7FFFu + ((v.u >> 16) & 1u);   // RNE
    return (unsigned short)(r >> 16);
}

// ---------------------------------------------------------------------------
// Pack kernel: P[r][c] = (bf16(M) << 16) | fp16(|W|).  One uint32 gather
// later instead of two fp32 loads; 64 MB array is fully L3-resident.
// fp16 for |w| (<= ~6) keeps exp-arg error ~5e-4*6 -> negligible.
// ---------------------------------------------------------------------------
__global__ __launch_bounds__(256) void pack_kernel(
    const float* __restrict__ M, const float* __restrict__ W,
    unsigned* __restrict__ P)
{
    const size_t i4 = ((size_t)blockIdx.x * 256 + threadIdx.x) * 4;
    const float4 m4 = *(const float4*)(M + i4);
    const float4 w4 = *(const float4*)(W + i4);
    uint4 o;
    o.x = ((unsigned)f2bf(m4.x) << 16) | (unsigned)__half_as_ushort(__float2half(fabsf(w4.x)));
    o.y = ((unsigned)f2bf(m4.y) << 16) | (unsigned)__half_as_ushort(__float2half(fabsf(w4.y)));
    o.z = ((unsigned)f2bf(m4.z) << 16) | (unsigned)__half_as_ushort(__float2half(fabsf(w4.z)));
    o.w = ((unsigned)f2bf(m4.w) << 16) | (unsigned)__half_as_ushort(__float2half(fabsf(w4.w)));
    *(uint4*)(P + i4) = o;
}

// ---------------------------------------------------------------------------
// Counting sort per batch (values < 4000). Ties in any order: the matmul is
// invariant to j-permutation. Replaces the 66-barrier-stage bitonic sort.
// ---------------------------------------------------------------------------
__global__ __launch_bounds__(1024) void sort_kernel(
    const int* __restrict__ stk_ten,
    int* __restrict__ sval,
    int* __restrict__ spos)
{
    __shared__ int hist[4000];
    __shared__ int base[4000];
    __shared__ int wsum[16];
    const int b = blockIdx.x, t = threadIdx.x;
    const int lane = t & 63, wv = t >> 6;
    const int* idxb = stk_ten + b * N;

    for (int j = t; j < 4000; j += 1024) hist[j] = 0;
    __syncthreads();
    const int v0 = idxb[t], v1 = idxb[t + 1024];
    atomicAdd(&hist[v0], 1);
    atomicAdd(&hist[v1], 1);
    __syncthreads();

    // scan: thread owns bins 4t..4t+3
    int h[4], c[4], run = 0;
    #pragma unroll
    for (int i = 0; i < 4; ++i) {
        const int bi = 4 * t + i;
        h[i] = (bi < 4000) ? hist[bi] : 0;
        run += h[i];
        c[i] = run;
    }
    const int tsum = run;
    int incl = tsum;
    #pragma unroll
    for (int d = 1; d < 64; d <<= 1) {
        const int tmp = __shfl_up(incl, d, 64);
        if (lane >= d) incl += tmp;
    }
    if (lane == 63) wsum[wv] = incl;
    __syncthreads();
    if (t < 16) {
        const int v = wsum[t];
        int iv = v;
        #pragma unroll
        for (int d = 1; d < 16; d <<= 1) {
            const int tmp = __shfl_up(iv, d, 64);
            if (lane >= d) iv += tmp;
        }
        wsum[t] = iv - v;               // exclusive across waves
    }
    __syncthreads();
    const int ex = incl - tsum + wsum[wv];
    #pragma unroll
    for (int i = 0; i < 4; ++i) {
        const int bi = 4 * t + i;
        if (bi < 4000) base[bi] = ex + c[i] - h[i];
    }
    __syncthreads();
    for (int j = t; j < 4000; j += 1024) hist[j] = 0;
    __syncthreads();
    {
        const int p0 = base[v0] + atomicAdd(&hist[v0], 1);
        sval[b * N + p0] = v0; spos[b * N + p0] = t;
        const int p1 = base[v1] + atomicAdd(&hist[v1], 1);
        sval[b * N + p1] = v1; spos[b * N + p1] = t + 1024;
    }
}

// ---------------------------------------------------------------------------
// xT[b][d][j_sorted] = bf16(x[b][spos[j]][d]).  4 MB, L2-resident B operand.
// ---------------------------------------------------------------------------
__global__ __launch_bounds__(256) void xt_kernel(
    const float* __restrict__ x,
    const int* __restrict__ spos,
    unsigned short* __restrict__ xT)
{
    __shared__ float xs[TJ][129];
    __shared__ int sp_s[TJ];
    const int t  = threadIdx.x;
    const int b  = blockIdx.x >> 5;
    const int jt = blockIdx.x & 31;
    const int j0 = jt * TJ;
    if (t < TJ) sp_s[t] = spos[b * N + j0 + t];
    __syncthreads();
    const int tx = t & 31, ty = t >> 5;
    const float* xb = x + (size_t)b * N * D;
    #pragma unroll
    for (int p = 0; p < 8; ++p) {
        const int r = ty + 8 * p;
        const float* src = xb + (size_t)sp_s[r] * D;
        #pragma unroll
        for (int i = 0; i < 4; ++i)
            xs[r][tx + 32 * i] = src[tx + 32 * i];
    }
    __syncthreads();
    const int jp = t & 31, dd0 = t >> 5;
    unsigned short* xTb = xT + (size_t)b * D * N;
    #pragma unroll
    for (int q = 0; q < 16; ++q) {
        const int dd = dd0 + 8 * q;
        const unsigned lo = f2bf(xs[2 * jp][dd]);
        const unsigned hi = f2bf(xs[2 * jp + 1][dd]);
        *(unsigned*)(xTb + (size_t)dd * N + j0 + 2 * jp) = (hi << 16) | lo;
    }
}

// ---------------------------------------------------------------------------
// Fused kernel, wave-autonomous K-split: wave w of a block handles K-quarter
// w for one 16-row i-tile x all 128 d.  NO __syncthreads in the K-loop ->
// the scattered-gather latency (issued one tile ahead into registers) is
// never drained by a barrier.  A-fragments via per-wave-private LDS region
// (same-wave lgkmcnt only); B read directly from L2-resident xT (full-line
// 16B/lane); per-lane denominator accumulation (no in-loop shuffles).
// Cross-wave acc + l reduction once at the end (2 barriers total).
// ---------------------------------------------------------------------------
__global__ __launch_bounds__(256, 2) void fused_kernel(
    const unsigned short* __restrict__ xT,
    const int* __restrict__ stk_ten,
    const unsigned* __restrict__ P,
    const int* __restrict__ sval,
    const int* __restrict__ spos,
    float* __restrict__ out)
{
    __shared__ __align__(16) unsigned short cs[KQ][IT * 72]; // per-wave private
    __shared__ float accbuf[KQ][IT][136];
    __shared__ float lbuf[KQ][IT];
    __shared__ int ri_s[IT];

    const int t    = threadIdx.x;
    const int lane = t & 63;
    const int w    = t >> 6;
    const int b    = blockIdx.x >> 7;            // 128 i-tiles per batch
    const int i0   = (blockIdx.x & 127) * IT;

    if (t < IT) ri_s[t] = stk_ten[b * N + i0 + t];
    __syncthreads();

    unsigned rowoff[IT];
    #pragma unroll
    for (int m = 0; m < IT; ++m) rowoff[m] = (unsigned)ri_s[m] * ST;

    const int* svb = sval + b * N;
    const int* spb = spos + b * N;
    const unsigned short* xTb = xT + (size_t)b * D * N;
    unsigned short* csw = &cs[w][0];

    f32x4 acc[8];
    #pragma unroll
    for (int nb = 0; nb < 8; ++nb)
        #pragma unroll
        for (int r = 0; r < 4; ++r) acc[nb][r] = 0.0f;
    float l_part[IT];
    #pragma unroll
    for (int m = 0; m < IT; ++m) l_part[m] = 0.0f;

    const int jbase = w * (TPW * TJ);
    const int brow  = lane & 15;
    const int bcol  = (lane >> 4) * 8;

    // prologue: tile 0 indices + gathers
    int cj = svb[jbase + lane];
    int pj = spb[jbase + lane];
    unsigned gv[IT];
    #pragma unroll
    for (int m = 0; m < IT; ++m) gv[m] = P[rowoff[m] + (unsigned)cj];

    for (int tt = 0; tt < TPW; ++tt) {
        const int j0  = jbase + tt * TJ;
        const int j0n = (tt == TPW - 1) ? jbase : j0 + TJ;   // clamped, discarded

        // issue next indices, then B(kc=0) — latency overlapped by coef VALU
        const int cjn = svb[j0n + lane];
        const int pjn = spb[j0n + lane];
        uint4 bv[8];
        #pragma unroll
        for (int nb = 0; nb < 8; ++nb)
            bv[nb] = *(const uint4*)(xTb + (size_t)(nb * 16 + brow) * N + j0 + bcol);

        // coefficients for tile tt from prefetched packed gathers
        #pragma unroll
        for (int m = 0; m < IT; ++m) {
            const unsigned u = gv[m];
            const float mf = __uint_as_float(u & 0xFFFF0000u);
            const float wf = __half2float(__ushort_as_half((unsigned short)(u & 0xFFFFu)));
            const bool diag = (pj == i0 + m);
            const float e = diag ? 1.0f : __expf(wf);   // diag: exp(0)=1
            l_part[m] += e;
            const float c = diag ? 0.0f : mf * e;
            csw[m * 72 + lane] = f2bf(c);
        }

        // A-fragments (same-wave LDS round-trip; lgkmcnt only, no barrier)
        const bf16x8 av0 = *(const bf16x8*)(csw + brow * 72 + bcol);
        const bf16x8 av1 = *(const bf16x8*)(csw + brow * 72 + 32 + bcol);

        // issue next tile's scattered gathers; land during MFMAs
        unsigned gvn[IT];
        #pragma unroll
        for (int m = 0; m < IT; ++m) gvn[m] = P[rowoff[m] + (unsigned)cjn];

        #pragma unroll
        for (int nb = 0; nb < 8; ++nb)
            acc[nb] = __builtin_amdgcn_mfma_f32_16x16x32_bf16(
                av0, *(const bf16x8*)&bv[nb], acc[nb], 0, 0, 0);
        #pragma unroll
        for (int nb = 0; nb < 8; ++nb)
            bv[nb] = *(const uint4*)(xTb + (size_t)(nb * 16 + brow) * N + j0 + 32 + bcol);
        #pragma unroll
        for (int nb = 0; nb < 8; ++nb)
            acc[nb] = __builtin_amdgcn_mfma_f32_16x16x32_bf16(
                av1, *(const bf16x8*)&bv[nb], acc[nb], 0, 0, 0);

        #pragma unroll
        for (int m = 0; m < IT; ++m) gv[m] = gvn[m];
        cj = cjn; pj = pjn;
    }

    // epilogue: l butterfly (once), acc -> LDS, cross-wave reduce
    #pragma unroll
    for (int m = 0; m < IT; ++m) {
        float v = l_part[m];
        #pragma unroll
        for (int d = 1; d < 64; d <<= 1) v += __shfl_xor(v, d, 64);
        if (lane == 0) lbuf[w][m] = v;
    }
    #pragma unroll
    for (int nb = 0; nb < 8; ++nb)
        #pragma unroll
        for (int r = 0; r < 4; ++r)
            accbuf[w][(lane >> 4) * 4 + r][nb * 16 + (lane & 15)] = acc[nb][r];
    __syncthreads();

    #pragma unroll
    for (int rr = 0; rr < 4; ++rr) {
        const int row = 4 * w + rr;
        const float linv = 1.0f /
            (lbuf[0][row] + lbuf[1][row] + lbuf[2][row] + lbuf[3][row]);
        #pragma unroll
        for (int p = 0; p < 2; ++p) {
            const int dd = lane + 64 * p;
            const float s = accbuf[0][row][dd] + accbuf[1][row][dd] +
                            accbuf[2][row][dd] + accbuf[3][row][dd];
            out[((size_t)(b * N + i0 + row) << 7) + dd] = s * linv;
        }
    }
}

extern "C" void kernel_launch(void* const* d_in, const int* in_sizes, int n_in,
                              void* d_out, int out_size, void* d_ws, size_t ws_size,
                              hipStream_t stream) {
    const float* x          = (const float*)d_in[0];
    const int*   stk_ten    = (const int*)d_in[1];
    const float* stk_matrix = (const float*)d_in[2];
    const float* stk_weight = (const float*)d_in[3];
    float* out = (float*)d_out;

    unsigned* P = (unsigned*)d_ws;                              // 64 MB
    int* sval = (int*)(P + (size_t)ST * ST);                    // 64 KB
    int* spos = sval + BATCH * N;                               // 64 KB
    unsigned short* xT = (unsigned short*)(spos + BATCH * N);   // 4 MB

    pack_kernel<<<(ST * ST) / 1024, 256, 0, stream>>>(stk_matrix, stk_weight, P);
    sort_kernel<<<BATCH, 1024, 0, stream>>>(stk_ten, sval, spos);
    xt_kernel<<<BATCH * (N / TJ), 256, 0, stream>>>(x, spos, xT);
    fused_kernel<<<BATCH * (N / IT), 256, 0, stream>>>(
        xT, stk_ten, P, sval, spos, out);
}